// Round 15
// baseline (185.773 us; speedup 1.0000x reference)
//
#include <hip/hip_runtime.h>

#define NNODE  50000
#define NHEDGE 10000
#define NEDGE  300000
#define HD     256
#define NS     (NHEDGE + NNODE)   // 60000 combined segments
#define CVT32_B (((NNODE*HD)/32 + 255) / 256) // 1563
#define PAD    32                 // one counter per 128B line
#define CAP_H  128                // hedge bucket capacity (mean 30, sigma 5.5)
#define CAP_N  48                 // node bucket capacity (mean 6, sigma 2.4)

typedef __attribute__((ext_vector_type(8))) short bf16x8;
typedef __attribute__((ext_vector_type(8))) unsigned short u16x8;
typedef __attribute__((ext_vector_type(4))) float f32x4;

__device__ __forceinline__ float prelu(float v, float a){ return v > 0.f ? v : a*v; }
__device__ __forceinline__ unsigned short f2bf(float f){
  unsigned u = __float_as_uint(f);
  return (unsigned short)((u + 0x7FFFu + ((u>>16)&1u)) >> 16);   // RNE
}
__device__ __forceinline__ float bf2f(unsigned short h){
  return __uint_as_float(((unsigned)h) << 16);
}
// ---- OCP e4m3 software encode/decode (RNE; saturating) ----
__device__ __forceinline__ unsigned f2fp8(float x){
  unsigned u = __float_as_uint(x * 0x1p-120f);
  unsigned s = (u >> 24) & 0x80u;
  unsigned m = u & 0x7fffffffu;
  unsigned r = m + 0x7ffffu + ((m >> 20) & 1u);
  unsigned v = r >> 20;
  if(v > 0x7eu) v = 0x7eu;
  return v | s;
}
__device__ __forceinline__ float fp82f(unsigned b){
  unsigned mag = (b & 0x7fu) << 20;
  float f = __uint_as_float(mag) * 0x1p120f;
  return __uint_as_float(__float_as_uint(f) | ((b & 0x80u) << 24));
}

// ---------------------------------------------------------------------------
// Merged prep:
//  blocks [0, HD): weight prep row o (Wb0 = bf16(W_n2e@W_in) [n][k],
//    Wb1 = bf16(W_e2n), bc = W_n2e@b_in + b_n2e) + zero padded cnts
//  blocks [HD, HD+CVT32_B): n_feat -> pre-scaled BF16 table, 32 elems/thread
//  (bf16 here: the fp8 n_feat table was the dominant error source; fp8 is
//   kept only for the efeat table whose error is attenuated by the e2n GEMM)
// ---------------------------------------------------------------------------
__global__ __launch_bounds__(256) void k_prep0(
    const float* __restrict__ W_in, const float* __restrict__ b_in,
    const float* __restrict__ W_n2e, const float* __restrict__ b_n2e,
    const float* __restrict__ W_e2n, const float* __restrict__ n_feat,
    const float* __restrict__ nrw,
    unsigned short* __restrict__ Wb0, unsigned short* __restrict__ Wb1,
    float* __restrict__ bc, int* __restrict__ cnts,
    unsigned short* __restrict__ tabw){
  int blk = blockIdx.x, t = threadIdx.x;
  if(blk < HD){
    int o = blk;
    int zi = o*256 + t;
    if(zi < NS) cnts[(size_t)zi*PAD] = 0;
    __shared__ float wn[HD];
    __shared__ float red[4];
    wn[t] = W_n2e[(size_t)o*HD + t];
    __syncthreads();
    float pb = wn[t] * b_in[t];
    #pragma unroll
    for(int d = 32; d > 0; d >>= 1) pb += __shfl_down(pb, d);
    if((t & 63) == 0) red[t >> 6] = pb;
    float acc = 0.f;
    #pragma unroll 8
    for(int h = 0; h < HD; ++h) acc += wn[h] * W_in[(size_t)h*HD + t];
    Wb0[(size_t)o*HD + t] = f2bf(acc);
    Wb1[(size_t)o*HD + t] = f2bf(W_e2n[(size_t)o*HD + t]);
    __syncthreads();
    if(t == 0) bc[o] = red[0] + red[1] + red[2] + red[3] + b_n2e[o];
  } else {
    int t32 = (blk - HD)*256 + t;
    if(t32 >= (NNODE*HD)/32) return;
    size_t f = (size_t)t32 * 32;
    float w = nrw[f >> 8];
    const float4* f4 = (const float4*)(n_feat + f);
    float4 a0 = f4[0], a1 = f4[1], a2 = f4[2], a3 = f4[3];
    float4 a4 = f4[4], a5 = f4[5], a6 = f4[6], a7 = f4[7];
    u16x8* out = (u16x8*)(tabw + f);
    u16x8 o0, o1, o2, o3;
    o0[0]=f2bf(w*a0.x); o0[1]=f2bf(w*a0.y); o0[2]=f2bf(w*a0.z); o0[3]=f2bf(w*a0.w);
    o0[4]=f2bf(w*a1.x); o0[5]=f2bf(w*a1.y); o0[6]=f2bf(w*a1.z); o0[7]=f2bf(w*a1.w);
    o1[0]=f2bf(w*a2.x); o1[1]=f2bf(w*a2.y); o1[2]=f2bf(w*a2.z); o1[3]=f2bf(w*a2.w);
    o1[4]=f2bf(w*a3.x); o1[5]=f2bf(w*a3.y); o1[6]=f2bf(w*a3.z); o1[7]=f2bf(w*a3.w);
    o2[0]=f2bf(w*a4.x); o2[1]=f2bf(w*a4.y); o2[2]=f2bf(w*a4.z); o2[3]=f2bf(w*a4.w);
    o2[4]=f2bf(w*a5.x); o2[5]=f2bf(w*a5.y); o2[6]=f2bf(w*a5.z); o2[7]=f2bf(w*a5.w);
    o3[0]=f2bf(w*a6.x); o3[1]=f2bf(w*a6.y); o3[2]=f2bf(w*a6.z); o3[3]=f2bf(w*a6.w);
    o3[4]=f2bf(w*a7.x); o3[5]=f2bf(w*a7.y); o3[6]=f2bf(w*a7.z); o3[7]=f2bf(w*a7.w);
    out[0] = o0; out[1] = o1; out[2] = o2; out[3] = o3;
  }
}

// ---------------------------------------------------------------------------
// Fixed-capacity bucket build: histogram IS the fill (no scan, no offsets).
//   hedge entry: (src node, nrw[src]);  node entry: (src hedge, hrw[src]).
// ---------------------------------------------------------------------------
__global__ void k_histfill(const int* __restrict__ node_idx, const int* __restrict__ hedge_idx,
                           const float* __restrict__ nrw, const float* __restrict__ hrw,
                           int* __restrict__ cnts,
                           int2* __restrict__ bkt_h, int2* __restrict__ bkt_n){
  int e = blockIdx.x*256 + threadIdx.x;
  if(e < NEDGE){
    int j = hedge_idx[e];
    int n = node_idx[e];
    int p = atomicAdd(&cnts[(size_t)j*PAD], 1);
    if(p < CAP_H) bkt_h[(size_t)j*CAP_H + p] = make_int2(n, __float_as_int(nrw[n]));
    int q = atomicAdd(&cnts[(size_t)(NHEDGE + n)*PAD], 1);
    if(q < CAP_N) bkt_n[(size_t)n*CAP_N + q] = make_int2(j, __float_as_int(hrw[j]));
  }
}

// ---------------------------------------------------------------------------
// Phase-1 aggregation from bf16 table (proven restructure): 8 half-waves per
// block, 2 hedges/block (4 chunks each), one-shot metadata preload, <=16
// back-to-back 16B row loads, LDS combine.
// ---------------------------------------------------------------------------
__global__ __launch_bounds__(256) void k_agg1(const unsigned short* __restrict__ tabw,
        const int2* __restrict__ bkt_h, const int* __restrict__ cnts,
        unsigned short* __restrict__ aggx_b, float* __restrict__ aggw){
  __shared__ float lacc[8][32][9];   // padded inner dim -> conflict-free
  __shared__ float lsw[8];
  int tid = threadIdx.x;
  int half = tid >> 5;               // 0..7
  int sl   = tid & 31;
  int lane = tid & 63;
  int hb   = lane & 32;              // base lane of this half within its wave
  int j = blockIdx.x*2 + (half >> 2);
  int c = half & 3;
  int cnt = cnts[(size_t)j*PAD]; if(cnt > CAP_H) cnt = CAP_H;
  int Lc = (cnt + 3) >> 2;
  int lo = c*Lc; if(lo > cnt) lo = cnt;
  int hi = lo + Lc; if(hi > cnt) hi = cnt;
  int Len = hi - lo;                 // 0..32
  const int2* bh = bkt_h + (size_t)j*CAP_H + lo;
  int2 meta = (sl < Len) ? bh[sl] : make_int2(0, 0);
  const u16x8* tab = (const u16x8*)tabw;   // 32 x u16x8 per 256-col row
  float acc[8] = {0.f,0.f,0.f,0.f,0.f,0.f,0.f,0.f};
  float sw = 0.f;
  u16x8 v[16];
  #pragma unroll
  for(int k = 0; k < 16; ++k){
    if(k < Len){
      int src = __shfl(meta.x, hb + k);
      sw += __int_as_float(__shfl(meta.y, hb + k));
      v[k] = tab[(size_t)src*32 + sl];
    }
  }
  #pragma unroll
  for(int k = 0; k < 16; ++k){
    if(k < Len){
      #pragma unroll
      for(int cc = 0; cc < 8; ++cc) acc[cc] += bf2f(v[k][cc]);
    }
  }
  for(int k = 16; k < Len; ++k){     // rare tail
    int2 mk = bh[k];
    sw += __int_as_float(mk.y);
    u16x8 cv = tab[(size_t)mk.x*32 + sl];
    #pragma unroll
    for(int cc = 0; cc < 8; ++cc) acc[cc] += bf2f(cv[cc]);
  }
  #pragma unroll
  for(int cc = 0; cc < 8; ++cc) lacc[half][sl][cc] = acc[cc];
  if(sl == 0) lsw[half] = sw;
  __syncthreads();
  if((half & 3) == 0){
    u16x8 ob;
    #pragma unroll
    for(int cc = 0; cc < 8; ++cc){
      float s = lacc[half][sl][cc] + lacc[half+1][sl][cc]
              + lacc[half+2][sl][cc] + lacc[half+3][sl][cc];
      ob[cc] = f2bf(s);
    }
    ((u16x8*)aggx_b)[(size_t)j*32 + sl] = ob;
    if(sl == 0) aggw[j] = lsw[half] + lsw[half+1] + lsw[half+2] + lsw[half+3];
  }
}

// ---------------------------------------------------------------------------
// GEMM0 (32 rows/block, 313 blocks):
//   efeat = prelu((aggx@Wc^T + aggw*bc)/hrs) -> out_ef (f32) + ef8 (fp8 e4m3)
// ---------------------------------------------------------------------------
__global__ __launch_bounds__(256) void k_gemm0(
    const unsigned short* __restrict__ xb, const unsigned short* __restrict__ Wb0,
    const float* __restrict__ aggw, const float* __restrict__ hrs,
    const float* __restrict__ bc, const float* __restrict__ alpha_p,
    float* __restrict__ out_ef, unsigned char* __restrict__ ef8){
  int wv = threadIdx.x >> 6, lane = threadIdx.x & 63;
  int m0 = blockIdx.x*32;        // block's 32 rows
  int n0 = wv*64;                // wave's 64-col tile
  int lr = lane & 15, lk = (lane >> 4) << 3, rb = (lane >> 4) << 2;
  float alpha = *alpha_p;
  const bf16x8 zero8 = {0,0,0,0,0,0,0,0};
  f32x4 acc[2][4];
  #pragma unroll
  for(int a = 0; a < 2; ++a)
    #pragma unroll
    for(int b = 0; b < 4; ++b) acc[a][b] = (f32x4){0.f,0.f,0.f,0.f};
  #pragma unroll
  for(int kc = 0; kc < HD; kc += 32){
    bf16x8 af[2], bfr[4];
    #pragma unroll
    for(int mi = 0; mi < 2; ++mi){
      int r = m0 + mi*16 + lr;
      af[mi] = (r < NHEDGE) ? *(const bf16x8*)&xb[(size_t)r*HD + kc + lk] : zero8;
    }
    #pragma unroll
    for(int ni = 0; ni < 4; ++ni){
      int c = n0 + ni*16 + lr;
      bfr[ni] = *(const bf16x8*)&Wb0[(size_t)c*HD + kc + lk];
    }
    #pragma unroll
    for(int mi = 0; mi < 2; ++mi)
      #pragma unroll
      for(int ni = 0; ni < 4; ++ni)
        acc[mi][ni] = __builtin_amdgcn_mfma_f32_16x16x32_bf16(af[mi], bfr[ni], acc[mi][ni], 0, 0, 0);
  }
  #pragma unroll
  for(int mi = 0; mi < 2; ++mi){
    #pragma unroll
    for(int jj = 0; jj < 4; ++jj){
      int r = m0 + mi*16 + rb + jj;
      if(r < NHEDGE){
        float ra = aggw[r];
        float inv = 1.f / hrs[r];
        #pragma unroll
        for(int ni = 0; ni < 4; ++ni){
          int c = n0 + ni*16 + lr;
          float v = (acc[mi][ni][jj] + ra*bc[c]) * inv;
          v = prelu(v, alpha);
          out_ef[(size_t)r*HD + c] = v;
          ef8[(size_t)r*HD + c] = (unsigned char)f2fp8(v);
        }
      }
    }
  }
}

// ---------------------------------------------------------------------------
// Phase-2 aggregation from fp8 efeat table (2.56 MB -> per-XCD L2 resident):
//  one half-wave per node, 8B/lane (uint2 = 8 fp8 cols), one-shot metadata,
//  <=12 back-to-back loads; weight applied in-register (exact).
//  h_pre[i] = sum_e hrw[j]*efeat[j]  (bf16 out), sw_n[i] = sum hrw.
// ---------------------------------------------------------------------------
__global__ __launch_bounds__(256) void k_agg2p(const unsigned char* __restrict__ ef8,
        const int2* __restrict__ bkt_n, const int* __restrict__ cnts,
        unsigned short* __restrict__ h_pre, float* __restrict__ sw_n){
  int tid = threadIdx.x;
  int half = tid >> 5;               // 0..7
  int sl   = tid & 31;
  int lane = tid & 63;
  int hb   = lane & 32;
  int i = blockIdx.x*8 + half;
  int cnt = cnts[(size_t)(NHEDGE + i)*PAD]; if(cnt > CAP_N) cnt = CAP_N;
  const int2* bn = bkt_n + (size_t)i*CAP_N;
  int2 meta = (sl < cnt) ? bn[sl] : make_int2(0, 0);
  const uint2* tab = (const uint2*)ef8;    // 32 x uint2 per 256-col row
  float acc[8] = {0.f,0.f,0.f,0.f,0.f,0.f,0.f,0.f};
  float sw = 0.f;
  uint2 v[12];
  float wv[12];
  #pragma unroll
  for(int k = 0; k < 12; ++k){
    if(k < cnt){
      int j = __shfl(meta.x, hb + k);
      wv[k] = __int_as_float(__shfl(meta.y, hb + k));
      sw += wv[k];
      v[k] = tab[(size_t)j*32 + sl];
    }
  }
  #pragma unroll
  for(int k = 0; k < 12; ++k){
    if(k < cnt){
      uint2 cv = v[k]; float w = wv[k];
      acc[0] += w*fp82f(cv.x);       acc[1] += w*fp82f(cv.x >> 8);
      acc[2] += w*fp82f(cv.x >> 16); acc[3] += w*fp82f(cv.x >> 24);
      acc[4] += w*fp82f(cv.y);       acc[5] += w*fp82f(cv.y >> 8);
      acc[6] += w*fp82f(cv.y >> 16); acc[7] += w*fp82f(cv.y >> 24);
    }
  }
  for(int k = 12; k < cnt; ++k){     // rare tail (P ~ 1%)
    int2 mk = bn[k];
    float w = __int_as_float(mk.y);
    sw += w;
    uint2 cv = tab[(size_t)mk.x*32 + sl];
    acc[0] += w*fp82f(cv.x);       acc[1] += w*fp82f(cv.x >> 8);
    acc[2] += w*fp82f(cv.x >> 16); acc[3] += w*fp82f(cv.x >> 24);
    acc[4] += w*fp82f(cv.y);       acc[5] += w*fp82f(cv.y >> 8);
    acc[6] += w*fp82f(cv.y >> 16); acc[7] += w*fp82f(cv.y >> 24);
  }
  u16x8 ob;
  #pragma unroll
  for(int c = 0; c < 8; ++c) ob[c] = f2bf(acc[c]);
  ((u16x8*)h_pre)[(size_t)i*32 + sl] = ob;
  if(sl == 0) sw_n[i] = sw;
}

// ---------------------------------------------------------------------------
// GEMM2 (post-aggregation e2n GEMM, 32 rows/block, 1563 blocks):
//   out_nodes = prelu((h_pre@W_e2n^T + sw_n*be) / nrs)
// ---------------------------------------------------------------------------
__global__ __launch_bounds__(256) void k_gemm2(
    const unsigned short* __restrict__ xb, const unsigned short* __restrict__ Wb1,
    const float* __restrict__ sw_n, const float* __restrict__ nrs,
    const float* __restrict__ be, const float* __restrict__ alpha_p,
    float* __restrict__ out_nodes){
  int wv = threadIdx.x >> 6, lane = threadIdx.x & 63;
  int m0 = blockIdx.x*32;
  int n0 = wv*64;
  int lr = lane & 15, lk = (lane >> 4) << 3, rb = (lane >> 4) << 2;
  float alpha = *alpha_p;
  const bf16x8 zero8 = {0,0,0,0,0,0,0,0};
  f32x4 acc[2][4];
  #pragma unroll
  for(int a = 0; a < 2; ++a)
    #pragma unroll
    for(int b = 0; b < 4; ++b) acc[a][b] = (f32x4){0.f,0.f,0.f,0.f};
  #pragma unroll
  for(int kc = 0; kc < HD; kc += 32){
    bf16x8 af[2], bfr[4];
    #pragma unroll
    for(int mi = 0; mi < 2; ++mi){
      int r = m0 + mi*16 + lr;
      af[mi] = (r < NNODE) ? *(const bf16x8*)&xb[(size_t)r*HD + kc + lk] : zero8;
    }
    #pragma unroll
    for(int ni = 0; ni < 4; ++ni){
      int c = n0 + ni*16 + lr;
      bfr[ni] = *(const bf16x8*)&Wb1[(size_t)c*HD + kc + lk];
    }
    #pragma unroll
    for(int mi = 0; mi < 2; ++mi)
      #pragma unroll
      for(int ni = 0; ni < 4; ++ni)
        acc[mi][ni] = __builtin_amdgcn_mfma_f32_16x16x32_bf16(af[mi], bfr[ni], acc[mi][ni], 0, 0, 0);
  }
  #pragma unroll
  for(int mi = 0; mi < 2; ++mi){
    #pragma unroll
    for(int jj = 0; jj < 4; ++jj){
      int r = m0 + mi*16 + rb + jj;
      if(r < NNODE){
        float sw = sw_n[r];
        float inv = 1.f / nrs[r];
        #pragma unroll
        for(int ni = 0; ni < 4; ++ni){
          int c = n0 + ni*16 + lr;
          float v = (acc[mi][ni][jj] + sw*be[c]) * inv;
          out_nodes[(size_t)r*HD + c] = prelu(v, alpha);
        }
      }
    }
  }
}

// ---------------------------------------------------------------------------
extern "C" void kernel_launch(void* const* d_in, const int* in_sizes, int n_in,
                              void* d_out, int out_size, void* d_ws, size_t ws_size,
                              hipStream_t stream){
  const float* n_feat   = (const float*)d_in[0];
  const int*   node_idx  = (const int*)d_in[2];
  const int*   hedge_idx = (const int*)d_in[3];
  const float* nrw  = (const float*)d_in[4];
  const float* nrs  = (const float*)d_in[5];
  const float* hrw  = (const float*)d_in[6];
  const float* hrs  = (const float*)d_in[7];
  const float* W_in  = (const float*)d_in[8];
  const float* b_in  = (const float*)d_in[9];
  const float* W_n2e = (const float*)d_in[10];
  const float* b_n2e = (const float*)d_in[11];
  const float* W_e2n = (const float*)d_in[12];
  const float* b_e2n = (const float*)d_in[13];
  const float* alpha = (const float*)d_in[14];

  float* out_nodes = (float*)d_out;
  float* out_efeat = out_nodes + (size_t)NNODE * HD;

  // bf16 pre-scaled n_feat table lives in the out_nodes region of d_out: it is
  // consumed only by k_agg1; k_gemm2 (the last kernel) fully overwrites it.
  unsigned short* tabw = (unsigned short*)out_nodes;

  char* p = (char*)d_ws;
  auto take = [&](size_t bytes) -> void* {
    void* r = (void*)p;
    p += (bytes + 255) & ~(size_t)255;
    return r;
  };
  unsigned short* Wb0     = (unsigned short*)take((size_t)HD*HD*2);
  unsigned short* Wb1     = (unsigned short*)take((size_t)HD*HD*2);
  float*          bc      = (float*)take(HD*4);
  float*          aggw    = (float*)take(NHEDGE*4);
  float*          sw_n    = (float*)take(NNODE*4);
  unsigned short* aggx_b  = (unsigned short*)take((size_t)NHEDGE*HD*2);
  unsigned char*  ef8     = (unsigned char*)take((size_t)NHEDGE*HD);
  unsigned short* h_pre   = (unsigned short*)take((size_t)NNODE*HD*2);
  int*            cnts    = (int*)take((size_t)NS*PAD*4);      // padded: 1 ctr / 128B
  int2*           bkt_h   = (int2*)take((size_t)NHEDGE*CAP_H*8);
  int2*           bkt_n   = (int2*)take((size_t)NNODE*CAP_N*8);

  k_prep0<<<HD + CVT32_B, 256, 0, stream>>>(W_in, b_in, W_n2e, b_n2e, W_e2n,
                                            n_feat, nrw, Wb0, Wb1, bc, cnts, tabw);
  k_histfill<<<(NEDGE+255)/256, 256, 0, stream>>>(node_idx, hedge_idx, nrw, hrw,
                                                  cnts, bkt_h, bkt_n);
  k_agg1<<<NHEDGE/2, 256, 0, stream>>>(tabw, bkt_h, cnts, aggx_b, aggw);
  k_gemm0<<<(NHEDGE + 31)/32, 256, 0, stream>>>(aggx_b, Wb0, aggw, hrs, bc, alpha,
                                                out_efeat, ef8);
  k_agg2p<<<NNODE/8, 256, 0, stream>>>(ef8, bkt_n, cnts, h_pre, sw_n);
  k_gemm2<<<(NNODE + 31)/32, 256, 0, stream>>>(h_pre, Wb1, sw_n, nrs, b_e2n, alpha,
                                               out_nodes);
}

// Round 16
// 133.266 us; speedup vs baseline: 1.3940x; 1.3940x over previous
//
#include <hip/hip_runtime.h>

#define NNODE  50000
#define NHEDGE 10000
#define NEDGE  300000
#define HD     256
#define NS     (NHEDGE + NNODE)   // 60000 combined segments
#define CVT32_B (((NNODE*HD)/32 + 255) / 256) // 1563
#define PAD    32                 // one counter per 128B line
#define CAP_H  128                // hedge bucket capacity (mean 30, sigma 5.5)
#define CAP_N  48                 // node bucket capacity (mean 6, sigma 2.4)

typedef __attribute__((ext_vector_type(8))) short bf16x8;
typedef __attribute__((ext_vector_type(8))) unsigned short u16x8;
typedef __attribute__((ext_vector_type(4))) float f32x4;

__device__ __forceinline__ float prelu(float v, float a){ return v > 0.f ? v : a*v; }
__device__ __forceinline__ unsigned short f2bf(float f){
  unsigned u = __float_as_uint(f);
  return (unsigned short)((u + 0x7FFFu + ((u>>16)&1u)) >> 16);   // RNE
}
__device__ __forceinline__ float bf2f(unsigned short h){
  return __uint_as_float(((unsigned)h) << 16);
}
// ---- OCP e4m3 software encode/decode (RNE; saturating) ----
__device__ __forceinline__ unsigned f2fp8(float x){
  unsigned u = __float_as_uint(x * 0x1p-120f);
  unsigned s = (u >> 24) & 0x80u;
  unsigned m = u & 0x7fffffffu;
  unsigned r = m + 0x7ffffu + ((m >> 20) & 1u);
  unsigned v = r >> 20;
  if(v > 0x7eu) v = 0x7eu;
  return v | s;
}
__device__ __forceinline__ float fp82f(unsigned b){
  unsigned mag = (b & 0x7fu) << 20;
  float f = __uint_as_float(mag) * 0x1p120f;
  return __uint_as_float(__float_as_uint(f) | ((b & 0x80u) << 24));
}

// ---------------------------------------------------------------------------
// Merged prep:
//  blocks [0, HD): weight prep row o (Wb0 = bf16(W_n2e@W_in) [n][k],
//    Wb1 = bf16(W_e2n), bc = W_n2e@b_in + b_n2e) + zero padded cnts
//  blocks [HD, HD+CVT32_B): n_feat -> pre-scaled fp8-e4m3 table, 32 elems/thread
// ---------------------------------------------------------------------------
__global__ __launch_bounds__(256) void k_prep0(
    const float* __restrict__ W_in, const float* __restrict__ b_in,
    const float* __restrict__ W_n2e, const float* __restrict__ b_n2e,
    const float* __restrict__ W_e2n, const float* __restrict__ n_feat,
    const float* __restrict__ nrw,
    unsigned short* __restrict__ Wb0, unsigned short* __restrict__ Wb1,
    float* __restrict__ bc, int* __restrict__ cnts,
    unsigned char* __restrict__ tab8){
  int blk = blockIdx.x, t = threadIdx.x;
  if(blk < HD){
    int o = blk;
    int zi = o*256 + t;
    if(zi < NS) cnts[(size_t)zi*PAD] = 0;
    __shared__ float wn[HD];
    __shared__ float red[4];
    wn[t] = W_n2e[(size_t)o*HD + t];
    __syncthreads();
    float pb = wn[t] * b_in[t];
    #pragma unroll
    for(int d = 32; d > 0; d >>= 1) pb += __shfl_down(pb, d);
    if((t & 63) == 0) red[t >> 6] = pb;
    float acc = 0.f;
    #pragma unroll 8
    for(int h = 0; h < HD; ++h) acc += wn[h] * W_in[(size_t)h*HD + t];
    Wb0[(size_t)o*HD + t] = f2bf(acc);
    Wb1[(size_t)o*HD + t] = f2bf(W_e2n[(size_t)o*HD + t]);
    __syncthreads();
    if(t == 0) bc[o] = red[0] + red[1] + red[2] + red[3] + b_n2e[o];
  } else {
    int t32 = (blk - HD)*256 + t;
    if(t32 >= (NNODE*HD)/32) return;
    size_t f = (size_t)t32 * 32;
    float w = nrw[f >> 8];
    const float4* f4 = (const float4*)(n_feat + f);
    unsigned q[8];
    #pragma unroll
    for(int g = 0; g < 8; ++g){
      float4 a = f4[g];
      q[g] =  f2fp8(w*a.x)        | (f2fp8(w*a.y) << 8)
           | (f2fp8(w*a.z) << 16) | (f2fp8(w*a.w) << 24);
    }
    uint4* out = (uint4*)(tab8 + f);
    out[0] = make_uint4(q[0], q[1], q[2], q[3]);
    out[1] = make_uint4(q[4], q[5], q[6], q[7]);
  }
}

// ---------------------------------------------------------------------------
// Fixed-capacity bucket build: histogram IS the fill (no scan, no offsets).
// ---------------------------------------------------------------------------
__global__ void k_histfill(const int* __restrict__ node_idx, const int* __restrict__ hedge_idx,
                           const float* __restrict__ nrw, int* __restrict__ cnts,
                           int2* __restrict__ bkt_h, int* __restrict__ bkt_n){
  int e = blockIdx.x*256 + threadIdx.x;
  if(e < NEDGE){
    int j = hedge_idx[e];
    int n = node_idx[e];
    int p = atomicAdd(&cnts[(size_t)j*PAD], 1);
    if(p < CAP_H) bkt_h[(size_t)j*CAP_H + p] = make_int2(n, __float_as_int(nrw[n]));
    int q = atomicAdd(&cnts[(size_t)(NHEDGE + n)*PAD], 1);
    if(q < CAP_N) bkt_n[(size_t)n*CAP_N + q] = j;
  }
}

// ---------------------------------------------------------------------------
// Phase-1 aggregation, concurrency-maximized:
//  - block = 256 threads = 8 half-waves; handles 2 hedges (4 chunks each).
//  - chunk = ceil(cnt/4) <= 32 rows; metadata preloaded in ONE coalesced load
//    (lane sl holds entry sl), fetched per-stage via __shfl (no serial chain).
//  - all <=16 row loads issued back-to-back (static unroll, predicated),
//    decode+accumulate after; rare Len>16 handled by fallback loop.
//  - partials combined in LDS (padded, conflict-free); owner half-wave writes.
// ---------------------------------------------------------------------------
__global__ __launch_bounds__(256) void k_agg1(const unsigned char* __restrict__ tab8,
        const int2* __restrict__ bkt_h, const int* __restrict__ cnts,
        unsigned short* __restrict__ aggx_b, float* __restrict__ aggw){
  __shared__ float lacc[8][32][9];   // padded inner dim -> conflict-free
  __shared__ float lsw[8];
  int tid = threadIdx.x;
  int half = tid >> 5;               // 0..7
  int sl   = tid & 31;
  int lane = tid & 63;
  int hb   = lane & 32;              // base lane of this half within its wave
  int j = blockIdx.x*2 + (half >> 2);
  int c = half & 3;
  int cnt = cnts[(size_t)j*PAD]; if(cnt > CAP_H) cnt = CAP_H;
  int Lc = (cnt + 3) >> 2;
  int lo = c*Lc; if(lo > cnt) lo = cnt;
  int hi = lo + Lc; if(hi > cnt) hi = cnt;
  int Len = hi - lo;                 // 0..32
  const int2* bh = bkt_h + (size_t)j*CAP_H + lo;
  int2 meta = (sl < Len) ? bh[sl] : make_int2(0, 0);
  const uint2* tab = (const uint2*)tab8;   // 32 x uint2 per 256-col row
  float acc[8] = {0.f,0.f,0.f,0.f,0.f,0.f,0.f,0.f};
  float sw = 0.f;
  uint2 v[16];
  #pragma unroll
  for(int k = 0; k < 16; ++k){
    if(k < Len){
      int src = __shfl(meta.x, hb + k);
      sw += __int_as_float(__shfl(meta.y, hb + k));
      v[k] = tab[(size_t)src*32 + sl];
    }
  }
  #pragma unroll
  for(int k = 0; k < 16; ++k){
    if(k < Len){
      uint2 cv = v[k];
      acc[0] += fp82f(cv.x);       acc[1] += fp82f(cv.x >> 8);
      acc[2] += fp82f(cv.x >> 16); acc[3] += fp82f(cv.x >> 24);
      acc[4] += fp82f(cv.y);       acc[5] += fp82f(cv.y >> 8);
      acc[6] += fp82f(cv.y >> 16); acc[7] += fp82f(cv.y >> 24);
    }
  }
  for(int k = 16; k < Len; ++k){
    int2 mk = bh[k];
    sw += __int_as_float(mk.y);
    uint2 cv = tab[(size_t)mk.x*32 + sl];
    acc[0] += fp82f(cv.x);       acc[1] += fp82f(cv.x >> 8);
    acc[2] += fp82f(cv.x >> 16); acc[3] += fp82f(cv.x >> 24);
    acc[4] += fp82f(cv.y);       acc[5] += fp82f(cv.y >> 8);
    acc[6] += fp82f(cv.y >> 16); acc[7] += fp82f(cv.y >> 24);
  }
  #pragma unroll
  for(int cc = 0; cc < 8; ++cc) lacc[half][sl][cc] = acc[cc];
  if(sl == 0) lsw[half] = sw;
  __syncthreads();
  if((half & 3) == 0){
    u16x8 ob;
    #pragma unroll
    for(int cc = 0; cc < 8; ++cc){
      float s = lacc[half][sl][cc] + lacc[half+1][sl][cc]
              + lacc[half+2][sl][cc] + lacc[half+3][sl][cc];
      ob[cc] = f2bf(s);
    }
    ((u16x8*)aggx_b)[(size_t)j*32 + sl] = ob;
    if(sl == 0) aggw[j] = lsw[half] + lsw[half+1] + lsw[half+2] + lsw[half+3];
  }
}

// ---------------------------------------------------------------------------
// Fused GEMM0+GEMM1, 32 rows per block (grid = 313 blocks).
// Phase A: efeat = prelu((aggx@Wc^T + aggw*bc)/hrs) -> out_ef (f32) + ef_b (bf16)
// Phase B: y = hrw*(efeat@W_e2n^T + be)             -> y_b (bf16)
// y_b aliases aggx_b: a block writes only rows it owns, after reading them.
// ---------------------------------------------------------------------------
__global__ __launch_bounds__(256) void k_gemm01(
    const unsigned short* __restrict__ xb, const unsigned short* __restrict__ Wb0,
    const unsigned short* __restrict__ Wb1,
    const float* __restrict__ aggw, const float* __restrict__ hrs,
    const float* __restrict__ hrw, const float* __restrict__ bc,
    const float* __restrict__ be, const float* __restrict__ alpha_p,
    float* __restrict__ out_ef, unsigned short* __restrict__ ef_b,
    unsigned short* __restrict__ y_b){
  int wv = threadIdx.x >> 6, lane = threadIdx.x & 63;
  int m0 = blockIdx.x*32;        // block's 32 rows
  int n0 = wv*64;                // wave's 64-col tile
  int lr = lane & 15, lk = (lane >> 4) << 3, rb = (lane >> 4) << 2;
  float alpha = *alpha_p;
  const bf16x8 zero8 = {0,0,0,0,0,0,0,0};
  // ---- phase A ----
  {
    f32x4 acc[2][4];
    #pragma unroll
    for(int a = 0; a < 2; ++a)
      #pragma unroll
      for(int b = 0; b < 4; ++b) acc[a][b] = (f32x4){0.f,0.f,0.f,0.f};
    #pragma unroll
    for(int kc = 0; kc < HD; kc += 32){
      bf16x8 af[2], bfr[4];
      #pragma unroll
      for(int mi = 0; mi < 2; ++mi){
        int r = m0 + mi*16 + lr;
        af[mi] = (r < NHEDGE) ? *(const bf16x8*)&xb[(size_t)r*HD + kc + lk] : zero8;
      }
      #pragma unroll
      for(int ni = 0; ni < 4; ++ni){
        int c = n0 + ni*16 + lr;
        bfr[ni] = *(const bf16x8*)&Wb0[(size_t)c*HD + kc + lk];
      }
      #pragma unroll
      for(int mi = 0; mi < 2; ++mi)
        #pragma unroll
        for(int ni = 0; ni < 4; ++ni)
          acc[mi][ni] = __builtin_amdgcn_mfma_f32_16x16x32_bf16(af[mi], bfr[ni], acc[mi][ni], 0, 0, 0);
    }
    #pragma unroll
    for(int mi = 0; mi < 2; ++mi){
      #pragma unroll
      for(int jj = 0; jj < 4; ++jj){
        int r = m0 + mi*16 + rb + jj;
        if(r < NHEDGE){
          float ra = aggw[r];
          float inv = 1.f / hrs[r];
          #pragma unroll
          for(int ni = 0; ni < 4; ++ni){
            int c = n0 + ni*16 + lr;
            float v = (acc[mi][ni][jj] + ra*bc[c]) * inv;
            v = prelu(v, alpha);
            out_ef[(size_t)r*HD + c] = v;
            ef_b[(size_t)r*HD + c] = f2bf(v);
          }
        }
      }
    }
  }
  __syncthreads();   // block's ef_b rows visible (stores drained to L2)
  // ---- phase B ----
  {
    f32x4 acc[2][4];
    #pragma unroll
    for(int a = 0; a < 2; ++a)
      #pragma unroll
      for(int b = 0; b < 4; ++b) acc[a][b] = (f32x4){0.f,0.f,0.f,0.f};
    #pragma unroll
    for(int kc = 0; kc < HD; kc += 32){
      bf16x8 af[2], bfr[4];
      #pragma unroll
      for(int mi = 0; mi < 2; ++mi){
        int r = m0 + mi*16 + lr;
        af[mi] = (r < NHEDGE) ? *(const bf16x8*)&ef_b[(size_t)r*HD + kc + lk] : zero8;
      }
      #pragma unroll
      for(int ni = 0; ni < 4; ++ni){
        int c = n0 + ni*16 + lr;
        bfr[ni] = *(const bf16x8*)&Wb1[(size_t)c*HD + kc + lk];
      }
      #pragma unroll
      for(int mi = 0; mi < 2; ++mi)
        #pragma unroll
        for(int ni = 0; ni < 4; ++ni)
          acc[mi][ni] = __builtin_amdgcn_mfma_f32_16x16x32_bf16(af[mi], bfr[ni], acc[mi][ni], 0, 0, 0);
    }
    #pragma unroll
    for(int mi = 0; mi < 2; ++mi){
      #pragma unroll
      for(int jj = 0; jj < 4; ++jj){
        int r = m0 + mi*16 + rb + jj;
        if(r < NHEDGE){
          float ra = hrw[r];
          #pragma unroll
          for(int ni = 0; ni < 4; ++ni){
            int c = n0 + ni*16 + lr;
            float v = ra * (acc[mi][ni][jj] + be[c]);
            y_b[(size_t)r*HD + c] = f2bf(v);
          }
        }
      }
    }
  }
}

// ---------------------------------------------------------------------------
// Phase-2 aggregation: 2 nodes per wave, 16B/lane, depth-4 prefetch + epilogue.
// ---------------------------------------------------------------------------
__global__ __launch_bounds__(256) void k_agg2(const unsigned short* __restrict__ yb,
        const int* __restrict__ bkt_n, const int* __restrict__ cnts,
        const float* __restrict__ nrs, const float* __restrict__ alpha_p,
        float* __restrict__ out_nodes){
  int wv = threadIdx.x >> 6, lane = threadIdx.x & 63;
  int sub = lane >> 5, sl = lane & 31;
  int i = blockIdx.x*8 + wv*2 + sub;
  int cnt = cnts[(size_t)(NHEDGE + i)*PAD]; if(cnt > CAP_N) cnt = CAP_N;
  const int* bn = bkt_n + (size_t)i*CAP_N;
  const u16x8* tab = (const u16x8*)yb;
  float acc[8] = {0.f,0.f,0.f,0.f,0.f,0.f,0.f,0.f};
  u16x8 z8 = {0,0,0,0,0,0,0,0};
  u16x8 v0=z8, v1=z8, v2=z8, v3=z8;
  if(cnt > 0){ int j = bn[0]; v0 = tab[(size_t)j*32 + sl]; }
  if(cnt > 1){ int j = bn[1]; v1 = tab[(size_t)j*32 + sl]; }
  if(cnt > 2){ int j = bn[2]; v2 = tab[(size_t)j*32 + sl]; }
  if(cnt > 3){ int j = bn[3]; v3 = tab[(size_t)j*32 + sl]; }
  int k = 0;
  while(k < cnt){
    { u16x8 cv = v0;
      if(k + 4 < cnt){ int j = bn[k+4]; v0 = tab[(size_t)j*32 + sl]; }
      #pragma unroll
      for(int c = 0; c < 8; ++c) acc[c] += bf2f(cv[c]); }
    if(++k >= cnt) break;
    { u16x8 cv = v1;
      if(k + 4 < cnt){ int j = bn[k+4]; v1 = tab[(size_t)j*32 + sl]; }
      #pragma unroll
      for(int c = 0; c < 8; ++c) acc[c] += bf2f(cv[c]); }
    if(++k >= cnt) break;
    { u16x8 cv = v2;
      if(k + 4 < cnt){ int j = bn[k+4]; v2 = tab[(size_t)j*32 + sl]; }
      #pragma unroll
      for(int c = 0; c < 8; ++c) acc[c] += bf2f(cv[c]); }
    if(++k >= cnt) break;
    { u16x8 cv = v3;
      if(k + 4 < cnt){ int j = bn[k+4]; v3 = tab[(size_t)j*32 + sl]; }
      #pragma unroll
      for(int c = 0; c < 8; ++c) acc[c] += bf2f(cv[c]); }
    ++k;
  }
  float inv = 1.f / nrs[i];
  float a = *alpha_p;
  float4 o1, o2;
  o1.x = prelu(acc[0]*inv, a); o1.y = prelu(acc[1]*inv, a);
  o1.z = prelu(acc[2]*inv, a); o1.w = prelu(acc[3]*inv, a);
  o2.x = prelu(acc[4]*inv, a); o2.y = prelu(acc[5]*inv, a);
  o2.z = prelu(acc[6]*inv, a); o2.w = prelu(acc[7]*inv, a);
  *(float4*)&out_nodes[(size_t)i*HD + sl*8]     = o1;
  *(float4*)&out_nodes[(size_t)i*HD + sl*8 + 4] = o2;
}

// ---------------------------------------------------------------------------
extern "C" void kernel_launch(void* const* d_in, const int* in_sizes, int n_in,
                              void* d_out, int out_size, void* d_ws, size_t ws_size,
                              hipStream_t stream){
  const float* n_feat   = (const float*)d_in[0];
  const int*   node_idx  = (const int*)d_in[2];
  const int*   hedge_idx = (const int*)d_in[3];
  const float* nrw  = (const float*)d_in[4];
  const float* nrs  = (const float*)d_in[5];
  const float* hrw  = (const float*)d_in[6];
  const float* hrs  = (const float*)d_in[7];
  const float* W_in  = (const float*)d_in[8];
  const float* b_in  = (const float*)d_in[9];
  const float* W_n2e = (const float*)d_in[10];
  const float* b_n2e = (const float*)d_in[11];
  const float* W_e2n = (const float*)d_in[12];
  const float* b_e2n = (const float*)d_in[13];
  const float* alpha = (const float*)d_in[14];

  float* out_nodes = (float*)d_out;
  float* out_efeat = out_nodes + (size_t)NNODE * HD;

  // fp8 pre-scaled n_feat table lives in the out_nodes region of d_out: it is
  // consumed only by k_agg1, and k_agg2 (the last kernel) fully overwrites it.
  unsigned char* tab8 = (unsigned char*)out_nodes;

  char* p = (char*)d_ws;
  auto take = [&](size_t bytes) -> void* {
    void* r = (void*)p;
    p += (bytes + 255) & ~(size_t)255;
    return r;
  };
  unsigned short* Wb0     = (unsigned short*)take((size_t)HD*HD*2);
  unsigned short* Wb1     = (unsigned short*)take((size_t)HD*HD*2);
  float*          bc      = (float*)take(HD*4);
  float*          aggw    = (float*)take(NHEDGE*4);
  unsigned short* aggx_b  = (unsigned short*)take((size_t)NHEDGE*HD*2);  // aliased as ybuf_b
  unsigned short* efeat_b = (unsigned short*)take((size_t)NHEDGE*HD*2);
  int*            cnts    = (int*)take((size_t)NS*PAD*4);      // padded: 1 ctr / 128B
  int2*           bkt_h   = (int2*)take((size_t)NHEDGE*CAP_H*8);
  int*            bkt_n   = (int*)take((size_t)NNODE*CAP_N*4);
  unsigned short* ybuf_b  = aggx_b;  // safe alias: see k_gemm01 header comment

  k_prep0<<<HD + CVT32_B, 256, 0, stream>>>(W_in, b_in, W_n2e, b_n2e, W_e2n,
                                            n_feat, nrw, Wb0, Wb1, bc, cnts, tab8);
  k_histfill<<<(NEDGE+255)/256, 256, 0, stream>>>(node_idx, hedge_idx, nrw,
                                                  cnts, bkt_h, bkt_n);
  k_agg1<<<NHEDGE/2, 256, 0, stream>>>(tab8, bkt_h, cnts, aggx_b, aggw);
  k_gemm01<<<(NHEDGE + 31)/32, 256, 0, stream>>>(aggx_b, Wb0, Wb1, aggw, hrs, hrw,
                                                 bc, b_e2n, alpha,
                                                 out_efeat, efeat_b, ybuf_b);
  k_agg2<<<NNODE/8, 256, 0, stream>>>(ybuf_b, bkt_n, cnts, nrs, alpha, out_nodes);
}

// Round 17
// 132.475 us; speedup vs baseline: 1.4023x; 1.0060x over previous
//
#include <hip/hip_runtime.h>

#define NNODE  50000
#define NHEDGE 10000
#define NEDGE  300000
#define HD     256
#define NS     (NHEDGE + NNODE)   // 60000 combined segments
#define CVT32_B (((NNODE*HD)/32 + 255) / 256) // 1563
#define PAD    8                  // one counter per 32B (4 ctrs/line; contention OK per r7/8)
#define CAP_H  128                // hedge bucket capacity (mean 30, sigma 5.5)
#define CAP_N  48                 // node bucket capacity (mean 6, sigma 2.4)

typedef __attribute__((ext_vector_type(8))) short bf16x8;
typedef __attribute__((ext_vector_type(8))) unsigned short u16x8;
typedef __attribute__((ext_vector_type(4))) float f32x4;

__device__ __forceinline__ float prelu(float v, float a){ return v > 0.f ? v : a*v; }
__device__ __forceinline__ unsigned short f2bf(float f){
  unsigned u = __float_as_uint(f);
  return (unsigned short)((u + 0x7FFFu + ((u>>16)&1u)) >> 16);   // RNE
}
__device__ __forceinline__ float bf2f(unsigned short h){
  return __uint_as_float(((unsigned)h) << 16);
}
// ---- OCP e4m3 software encode/decode (RNE; saturating) ----
__device__ __forceinline__ unsigned f2fp8(float x){
  unsigned u = __float_as_uint(x * 0x1p-120f);
  unsigned s = (u >> 24) & 0x80u;
  unsigned m = u & 0x7fffffffu;
  unsigned r = m + 0x7ffffu + ((m >> 20) & 1u);
  unsigned v = r >> 20;
  if(v > 0x7eu) v = 0x7eu;
  return v | s;
}
__device__ __forceinline__ float fp82f(unsigned b){
  unsigned mag = (b & 0x7fu) << 20;
  float f = __uint_as_float(mag) * 0x1p120f;
  return __uint_as_float(__float_as_uint(f) | ((b & 0x80u) << 24));
}

// ---------------------------------------------------------------------------
// Merged prep:
//  blocks [0, HD): weight prep row o (Wb0 = bf16(W_n2e@W_in) [n][k],
//    Wb1 = bf16(W_e2n), bc = W_n2e@b_in + b_n2e) + zero padded cnts
//  blocks [HD, HD+CVT32_B): n_feat -> pre-scaled fp8-e4m3 table, 32 elems/thread
// ---------------------------------------------------------------------------
__global__ __launch_bounds__(256) void k_prep0(
    const float* __restrict__ W_in, const float* __restrict__ b_in,
    const float* __restrict__ W_n2e, const float* __restrict__ b_n2e,
    const float* __restrict__ W_e2n, const float* __restrict__ n_feat,
    const float* __restrict__ nrw,
    unsigned short* __restrict__ Wb0, unsigned short* __restrict__ Wb1,
    float* __restrict__ bc, int* __restrict__ cnts,
    unsigned char* __restrict__ tab8){
  int blk = blockIdx.x, t = threadIdx.x;
  if(blk < HD){
    int o = blk;
    int zi = o*256 + t;
    if(zi < NS) cnts[(size_t)zi*PAD] = 0;
    __shared__ float wn[HD];
    __shared__ float red[4];
    wn[t] = W_n2e[(size_t)o*HD + t];
    __syncthreads();
    float pb = wn[t] * b_in[t];
    #pragma unroll
    for(int d = 32; d > 0; d >>= 1) pb += __shfl_down(pb, d);
    if((t & 63) == 0) red[t >> 6] = pb;
    float acc = 0.f;
    #pragma unroll 8
    for(int h = 0; h < HD; ++h) acc += wn[h] * W_in[(size_t)h*HD + t];
    Wb0[(size_t)o*HD + t] = f2bf(acc);
    Wb1[(size_t)o*HD + t] = f2bf(W_e2n[(size_t)o*HD + t]);
    __syncthreads();
    if(t == 0) bc[o] = red[0] + red[1] + red[2] + red[3] + b_n2e[o];
  } else {
    int t32 = (blk - HD)*256 + t;
    if(t32 >= (NNODE*HD)/32) return;
    size_t f = (size_t)t32 * 32;
    float w = nrw[f >> 8];
    const float4* f4 = (const float4*)(n_feat + f);
    unsigned q[8];
    #pragma unroll
    for(int g = 0; g < 8; ++g){
      float4 a = f4[g];
      q[g] =  f2fp8(w*a.x)        | (f2fp8(w*a.y) << 8)
           | (f2fp8(w*a.z) << 16) | (f2fp8(w*a.w) << 24);
    }
    uint4* out = (uint4*)(tab8 + f);
    out[0] = make_uint4(q[0], q[1], q[2], q[3]);
    out[1] = make_uint4(q[4], q[5], q[6], q[7]);
  }
}

// ---------------------------------------------------------------------------
// Fixed-capacity bucket build: histogram IS the fill (no scan, no offsets).
// Buckets are int-only (src index); weights gathered later from L2-hot tables.
// ---------------------------------------------------------------------------
__global__ void k_histfill(const int* __restrict__ node_idx, const int* __restrict__ hedge_idx,
                           int* __restrict__ cnts,
                           int* __restrict__ bkt_h, int* __restrict__ bkt_n){
  int e = blockIdx.x*256 + threadIdx.x;
  if(e < NEDGE){
    int j = hedge_idx[e];
    int n = node_idx[e];
    int p = atomicAdd(&cnts[(size_t)j*PAD], 1);
    if(p < CAP_H) bkt_h[(size_t)j*CAP_H + p] = n;
    int q = atomicAdd(&cnts[(size_t)(NHEDGE + n)*PAD], 1);
    if(q < CAP_N) bkt_n[(size_t)n*CAP_N + q] = j;
  }
}

// ---------------------------------------------------------------------------
// Phase-1 aggregation, concurrency-maximized:
//  - block = 256 threads = 8 half-waves; handles 2 hedges (4 chunks each).
//  - chunk = ceil(cnt/4) <= 32 rows; metadata preloaded in ONE coalesced load
//    (lane sl holds entry sl); per-lane nrw gather issued alongside (L2-hot
//    200KB table, off the row-load critical path).
//  - all <=16 row loads issued back-to-back (static unroll, predicated),
//    decode+accumulate after; rare Len>16 handled by fallback loop.
//  - partials combined in LDS (padded, conflict-free); owner half-wave writes.
// ---------------------------------------------------------------------------
__global__ __launch_bounds__(256) void k_agg1(const unsigned char* __restrict__ tab8,
        const int* __restrict__ bkt_h, const int* __restrict__ cnts,
        const float* __restrict__ nrw,
        unsigned short* __restrict__ aggx_b, float* __restrict__ aggw){
  __shared__ float lacc[8][32][9];   // padded inner dim -> conflict-free
  __shared__ float lsw[8];
  int tid = threadIdx.x;
  int half = tid >> 5;               // 0..7
  int sl   = tid & 31;
  int lane = tid & 63;
  int hb   = lane & 32;              // base lane of this half within its wave
  int j = blockIdx.x*2 + (half >> 2);
  int c = half & 3;
  int cnt = cnts[(size_t)j*PAD]; if(cnt > CAP_H) cnt = CAP_H;
  int Lc = (cnt + 3) >> 2;
  int lo = c*Lc; if(lo > cnt) lo = cnt;
  int hi = lo + Lc; if(hi > cnt) hi = cnt;
  int Len = hi - lo;                 // 0..32
  const int* bh = bkt_h + (size_t)j*CAP_H + lo;
  // one-shot metadata preload: lane sl holds entry sl of this chunk,
  // plus its weight (independent L2 gather, issued immediately after)
  int meta = (sl < Len) ? bh[sl] : 0;
  float w  = (sl < Len) ? nrw[meta] : 0.f;
  const uint2* tab = (const uint2*)tab8;   // 32 x uint2 per 256-col row
  float acc[8] = {0.f,0.f,0.f,0.f,0.f,0.f,0.f,0.f};
  float sw = 0.f;
  uint2 v[16];
  #pragma unroll
  for(int k = 0; k < 16; ++k){
    if(k < Len){
      int src = __shfl(meta, hb + k);
      sw += __shfl(w, hb + k);
      v[k] = tab[(size_t)src*32 + sl];
    }
  }
  #pragma unroll
  for(int k = 0; k < 16; ++k){
    if(k < Len){
      uint2 cv = v[k];
      acc[0] += fp82f(cv.x);       acc[1] += fp82f(cv.x >> 8);
      acc[2] += fp82f(cv.x >> 16); acc[3] += fp82f(cv.x >> 24);
      acc[4] += fp82f(cv.y);       acc[5] += fp82f(cv.y >> 8);
      acc[6] += fp82f(cv.y >> 16); acc[7] += fp82f(cv.y >> 24);
    }
  }
  for(int k = 16; k < Len; ++k){     // rare tail
    int src = bh[k];
    sw += nrw[src];
    uint2 cv = tab[(size_t)src*32 + sl];
    acc[0] += fp82f(cv.x);       acc[1] += fp82f(cv.x >> 8);
    acc[2] += fp82f(cv.x >> 16); acc[3] += fp82f(cv.x >> 24);
    acc[4] += fp82f(cv.y);       acc[5] += fp82f(cv.y >> 8);
    acc[6] += fp82f(cv.y >> 16); acc[7] += fp82f(cv.y >> 24);
  }
  #pragma unroll
  for(int cc = 0; cc < 8; ++cc) lacc[half][sl][cc] = acc[cc];
  if(sl == 0) lsw[half] = sw;
  __syncthreads();
  if((half & 3) == 0){
    u16x8 ob;
    #pragma unroll
    for(int cc = 0; cc < 8; ++cc){
      float s = lacc[half][sl][cc] + lacc[half+1][sl][cc]
              + lacc[half+2][sl][cc] + lacc[half+3][sl][cc];
      ob[cc] = f2bf(s);
    }
    ((u16x8*)aggx_b)[(size_t)j*32 + sl] = ob;
    if(sl == 0) aggw[j] = lsw[half] + lsw[half+1] + lsw[half+2] + lsw[half+3];
  }
}

// ---------------------------------------------------------------------------
// Fused GEMM0+GEMM1, 32 rows per block (grid = 313 blocks).
// Phase A: efeat = prelu((aggx@Wc^T + aggw*bc)/hrs) -> out_ef (f32) + ef_b (bf16)
// Phase B: y = hrw*(efeat@W_e2n^T + be)             -> y_b (bf16)
// y_b aliases aggx_b: a block writes only rows it owns, after reading them.
// ---------------------------------------------------------------------------
__global__ __launch_bounds__(256) void k_gemm01(
    const unsigned short* __restrict__ xb, const unsigned short* __restrict__ Wb0,
    const unsigned short* __restrict__ Wb1,
    const float* __restrict__ aggw, const float* __restrict__ hrs,
    const float* __restrict__ hrw, const float* __restrict__ bc,
    const float* __restrict__ be, const float* __restrict__ alpha_p,
    float* __restrict__ out_ef, unsigned short* __restrict__ ef_b,
    unsigned short* __restrict__ y_b){
  int wv = threadIdx.x >> 6, lane = threadIdx.x & 63;
  int m0 = blockIdx.x*32;        // block's 32 rows
  int n0 = wv*64;                // wave's 64-col tile
  int lr = lane & 15, lk = (lane >> 4) << 3, rb = (lane >> 4) << 2;
  float alpha = *alpha_p;
  const bf16x8 zero8 = {0,0,0,0,0,0,0,0};
  // ---- phase A ----
  {
    f32x4 acc[2][4];
    #pragma unroll
    for(int a = 0; a < 2; ++a)
      #pragma unroll
      for(int b = 0; b < 4; ++b) acc[a][b] = (f32x4){0.f,0.f,0.f,0.f};
    #pragma unroll
    for(int kc = 0; kc < HD; kc += 32){
      bf16x8 af[2], bfr[4];
      #pragma unroll
      for(int mi = 0; mi < 2; ++mi){
        int r = m0 + mi*16 + lr;
        af[mi] = (r < NHEDGE) ? *(const bf16x8*)&xb[(size_t)r*HD + kc + lk] : zero8;
      }
      #pragma unroll
      for(int ni = 0; ni < 4; ++ni){
        int c = n0 + ni*16 + lr;
        bfr[ni] = *(const bf16x8*)&Wb0[(size_t)c*HD + kc + lk];
      }
      #pragma unroll
      for(int mi = 0; mi < 2; ++mi)
        #pragma unroll
        for(int ni = 0; ni < 4; ++ni)
          acc[mi][ni] = __builtin_amdgcn_mfma_f32_16x16x32_bf16(af[mi], bfr[ni], acc[mi][ni], 0, 0, 0);
    }
    #pragma unroll
    for(int mi = 0; mi < 2; ++mi){
      #pragma unroll
      for(int jj = 0; jj < 4; ++jj){
        int r = m0 + mi*16 + rb + jj;
        if(r < NHEDGE){
          float ra = aggw[r];
          float inv = 1.f / hrs[r];
          #pragma unroll
          for(int ni = 0; ni < 4; ++ni){
            int c = n0 + ni*16 + lr;
            float v = (acc[mi][ni][jj] + ra*bc[c]) * inv;
            v = prelu(v, alpha);
            out_ef[(size_t)r*HD + c] = v;
            ef_b[(size_t)r*HD + c] = f2bf(v);
          }
        }
      }
    }
  }
  __syncthreads();   // block's ef_b rows visible (stores drained to L2)
  // ---- phase B ----
  {
    f32x4 acc[2][4];
    #pragma unroll
    for(int a = 0; a < 2; ++a)
      #pragma unroll
      for(int b = 0; b < 4; ++b) acc[a][b] = (f32x4){0.f,0.f,0.f,0.f};
    #pragma unroll
    for(int kc = 0; kc < HD; kc += 32){
      bf16x8 af[2], bfr[4];
      #pragma unroll
      for(int mi = 0; mi < 2; ++mi){
        int r = m0 + mi*16 + lr;
        af[mi] = (r < NHEDGE) ? *(const bf16x8*)&ef_b[(size_t)r*HD + kc + lk] : zero8;
      }
      #pragma unroll
      for(int ni = 0; ni < 4; ++ni){
        int c = n0 + ni*16 + lr;
        bfr[ni] = *(const bf16x8*)&Wb1[(size_t)c*HD + kc + lk];
      }
      #pragma unroll
      for(int mi = 0; mi < 2; ++mi)
        #pragma unroll
        for(int ni = 0; ni < 4; ++ni)
          acc[mi][ni] = __builtin_amdgcn_mfma_f32_16x16x32_bf16(af[mi], bfr[ni], acc[mi][ni], 0, 0, 0);
    }
    #pragma unroll
    for(int mi = 0; mi < 2; ++mi){
      #pragma unroll
      for(int jj = 0; jj < 4; ++jj){
        int r = m0 + mi*16 + rb + jj;
        if(r < NHEDGE){
          float ra = hrw[r];
          #pragma unroll
          for(int ni = 0; ni < 4; ++ni){
            int c = n0 + ni*16 + lr;
            float v = ra * (acc[mi][ni][jj] + be[c]);
            y_b[(size_t)r*HD + c] = f2bf(v);
          }
        }
      }
    }
  }
}

// ---------------------------------------------------------------------------
// Phase-2 aggregation: 2 nodes per wave, 16B/lane, depth-4 prefetch + epilogue.
// ---------------------------------------------------------------------------
__global__ __launch_bounds__(256) void k_agg2(const unsigned short* __restrict__ yb,
        const int* __restrict__ bkt_n, const int* __restrict__ cnts,
        const float* __restrict__ nrs, const float* __restrict__ alpha_p,
        float* __restrict__ out_nodes){
  int wv = threadIdx.x >> 6, lane = threadIdx.x & 63;
  int sub = lane >> 5, sl = lane & 31;
  int i = blockIdx.x*8 + wv*2 + sub;
  int cnt = cnts[(size_t)(NHEDGE + i)*PAD]; if(cnt > CAP_N) cnt = CAP_N;
  const int* bn = bkt_n + (size_t)i*CAP_N;
  const u16x8* tab = (const u16x8*)yb;
  float acc[8] = {0.f,0.f,0.f,0.f,0.f,0.f,0.f,0.f};
  u16x8 z8 = {0,0,0,0,0,0,0,0};
  u16x8 v0=z8, v1=z8, v2=z8, v3=z8;
  if(cnt > 0){ int j = bn[0]; v0 = tab[(size_t)j*32 + sl]; }
  if(cnt > 1){ int j = bn[1]; v1 = tab[(size_t)j*32 + sl]; }
  if(cnt > 2){ int j = bn[2]; v2 = tab[(size_t)j*32 + sl]; }
  if(cnt > 3){ int j = bn[3]; v3 = tab[(size_t)j*32 + sl]; }
  int k = 0;
  while(k < cnt){
    { u16x8 cv = v0;
      if(k + 4 < cnt){ int j = bn[k+4]; v0 = tab[(size_t)j*32 + sl]; }
      #pragma unroll
      for(int c = 0; c < 8; ++c) acc[c] += bf2f(cv[c]); }
    if(++k >= cnt) break;
    { u16x8 cv = v1;
      if(k + 4 < cnt){ int j = bn[k+4]; v1 = tab[(size_t)j*32 + sl]; }
      #pragma unroll
      for(int c = 0; c < 8; ++c) acc[c] += bf2f(cv[c]); }
    if(++k >= cnt) break;
    { u16x8 cv = v2;
      if(k + 4 < cnt){ int j = bn[k+4]; v2 = tab[(size_t)j*32 + sl]; }
      #pragma unroll
      for(int c = 0; c < 8; ++c) acc[c] += bf2f(cv[c]); }
    if(++k >= cnt) break;
    { u16x8 cv = v3;
      if(k + 4 < cnt){ int j = bn[k+4]; v3 = tab[(size_t)j*32 + sl]; }
      #pragma unroll
      for(int c = 0; c < 8; ++c) acc[c] += bf2f(cv[c]); }
    ++k;
  }
  float inv = 1.f / nrs[i];
  float a = *alpha_p;
  float4 o1, o2;
  o1.x = prelu(acc[0]*inv, a); o1.y = prelu(acc[1]*inv, a);
  o1.z = prelu(acc[2]*inv, a); o1.w = prelu(acc[3]*inv, a);
  o2.x = prelu(acc[4]*inv, a); o2.y = prelu(acc[5]*inv, a);
  o2.z = prelu(acc[6]*inv, a); o2.w = prelu(acc[7]*inv, a);
  *(float4*)&out_nodes[(size_t)i*HD + sl*8]     = o1;
  *(float4*)&out_nodes[(size_t)i*HD + sl*8 + 4] = o2;
}

// ---------------------------------------------------------------------------
extern "C" void kernel_launch(void* const* d_in, const int* in_sizes, int n_in,
                              void* d_out, int out_size, void* d_ws, size_t ws_size,
                              hipStream_t stream){
  const float* n_feat   = (const float*)d_in[0];
  const int*   node_idx  = (const int*)d_in[2];
  const int*   hedge_idx = (const int*)d_in[3];
  const float* nrw  = (const float*)d_in[4];
  const float* nrs  = (const float*)d_in[5];
  const float* hrw  = (const float*)d_in[6];
  const float* hrs  = (const float*)d_in[7];
  const float* W_in  = (const float*)d_in[8];
  const float* b_in  = (const float*)d_in[9];
  const float* W_n2e = (const float*)d_in[10];
  const float* b_n2e = (const float*)d_in[11];
  const float* W_e2n = (const float*)d_in[12];
  const float* b_e2n = (const float*)d_in[13];
  const float* alpha = (const float*)d_in[14];

  float* out_nodes = (float*)d_out;
  float* out_efeat = out_nodes + (size_t)NNODE * HD;

  // fp8 pre-scaled n_feat table lives in the out_nodes region of d_out: it is
  // consumed only by k_agg1, and k_agg2 (the last kernel) fully overwrites it.
  unsigned char* tab8 = (unsigned char*)out_nodes;

  char* p = (char*)d_ws;
  auto take = [&](size_t bytes) -> void* {
    void* r = (void*)p;
    p += (bytes + 255) & ~(size_t)255;
    return r;
  };
  unsigned short* Wb0     = (unsigned short*)take((size_t)HD*HD*2);
  unsigned short* Wb1     = (unsigned short*)take((size_t)HD*HD*2);
  float*          bc      = (float*)take(HD*4);
  float*          aggw    = (float*)take(NHEDGE*4);
  unsigned short* aggx_b  = (unsigned short*)take((size_t)NHEDGE*HD*2);  // aliased as ybuf_b
  unsigned short* efeat_b = (unsigned short*)take((size_t)NHEDGE*HD*2);
  int*            cnts    = (int*)take((size_t)NS*PAD*4);      // padded: 1 ctr / 32B
  int*            bkt_h   = (int*)take((size_t)NHEDGE*CAP_H*4);
  int*            bkt_n   = (int*)take((size_t)NNODE*CAP_N*4);
  unsigned short* ybuf_b  = aggx_b;  // safe alias: see k_gemm01 header comment

  k_prep0<<<HD + CVT32_B, 256, 0, stream>>>(W_in, b_in, W_n2e, b_n2e, W_e2n,
                                            n_feat, nrw, Wb0, Wb1, bc, cnts, tab8);
  k_histfill<<<(NEDGE+255)/256, 256, 0, stream>>>(node_idx, hedge_idx,
                                                  cnts, bkt_h, bkt_n);
  k_agg1<<<NHEDGE/2, 256, 0, stream>>>(tab8, bkt_h, cnts, nrw, aggx_b, aggw);
  k_gemm01<<<(NHEDGE + 31)/32, 256, 0, stream>>>(aggx_b, Wb0, Wb1, aggw, hrs, hrw,
                                                 bc, b_e2n, alpha,
                                                 out_efeat, efeat_b, ybuf_b);
  k_agg2<<<NNODE/8, 256, 0, stream>>>(ybuf_b, bkt_n, cnts, nrs, alpha, out_nodes);
}